// Round 10
// baseline (144.933 us; speedup 1.0000x reference)
//
#include <hip/hip_runtime.h>

#define N 16384
#define TPB 256
#define INF_BITS 0x7F800000

// ================= MFMA path =================
// d^2 tile = 32x32 via v_mfma_f32_32x32x16_bf16, K=16 slots encode
// -2 a.b (12 slots, hi/lo bf16 split, products exact) + |a|^2 + |b|^2 (4 slots).
// Geometry: queries on A rows (resident), refs streamed on B cols; reduction =
// lane-shuffle min over cols + row-formula publish (rounds 1/6/7/8/9 VERIFIED).
// HARD RULES:
//  - NO inline asm touching MFMA results (rounds 2+3 failed; 1/6-9 passed).
//  - K-loop structure: EXACT round-6 (42.5us, best). Rounds 7 (occupancy),
//    8 (register pipeline), 9 (LDS staging) all regressed — the K-loop is a
//    measured local optimum; do not re-touch without new counter evidence.
// This round attacks the ~47-54us of fixed overhead (stable across r0-r9):
//  - reduce_kernel folded into chamfer via last-block pattern (one less launch)
//  - pack input reads coalesced via LDS staging (was 3 scalar HBM loads/thread)
#define NT32 (N / 32)                 // 512 tiles per side
#define MT 4                          // query tiles per wave (A frags, resident)
#define NSTRIP (NT32 / MT)            // 128
#define NJSPLIT 8                     // ref-column splits per pass
#define JW (NT32 / NJSPLIT)           // 64 ref tiles per wave
#define NWAVES (2 * NSTRIP * NJSPLIT) // 2048
#define NBLK_MFMA (NWAVES / 4)        // 512 blocks = 2/CU
#define FRAG_U4 (NT32 * 64)           // uint4 per fragment array (512 KB)
#define WS_NEED_MFMA (4ull * FRAG_U4 * sizeof(uint4) + 2ull * N * sizeof(int) + 16)

using bf16x8 = __attribute__((ext_vector_type(8))) short;
using fx16   = __attribute__((ext_vector_type(16))) float;

__device__ __forceinline__ unsigned short bf16_rn(float f) {
    unsigned u = __float_as_uint(f);
    u += 0x7FFFu + ((u >> 16) & 1u);        // round-to-nearest-even
    return (unsigned short)(u >> 16);
}
__device__ __forceinline__ float bf16f(unsigned short h) {
    return __uint_as_float(((unsigned)h) << 16);
}
__device__ __forceinline__ uint4 pack8(const unsigned short* a) {
    return make_uint4((unsigned)a[0] | ((unsigned)a[1] << 16),
                      (unsigned)a[2] | ((unsigned)a[3] << 16),
                      (unsigned)a[4] | ((unsigned)a[5] << 16),
                      (unsigned)a[6] | ((unsigned)a[7] << 16));
}

// frags layout (uint4 units): [Q0 | Q1 | R0 | R1], each FRAG_U4.
// Tile t, lane l holds 8 bf16 = k-slots (l>>5)*8..+7 for point (t*32 + (l&31)).
// A and B use the SAME (lane,elem)->k packing, so the MFMA pairing is correct
// regardless of the HW's internal k mapping (verified: rounds 1/6/7/8/9).
// Input staging: 128 blocks of 256 pts; N/TPB = 64 so no block straddles the
// p_hat/p boundary. 192 coalesced float4 loads -> LDS; stride-3 float reads
// are bank-conflict-free (gcd(3,32)=1).
__global__ void pack_mfma(const float* __restrict__ p_hat, const float* __restrict__ p,
                          uint4* __restrict__ frags, int* __restrict__ minbuf,
                          int* __restrict__ done)
{
    __shared__ float sIn[TPB * 3];
    int t   = (int)threadIdx.x;
    int idx = (int)blockIdx.x * TPB + t;
    if (idx == 0) *done = 0;                 // re-zeroed every graph replay
    minbuf[idx] = INF_BITS;

    const float* src = (idx < N) ? p_hat : p;
    int fbase = ((int)blockIdx.x & 63) * (TPB * 3);
    if (t < (TPB * 3) / 4) {
        float4 v = *(const float4*)(src + fbase + t * 4);
        *(float4*)&sIn[t * 4] = v;
    }
    __syncthreads();
    float x = sIn[3 * t + 0], y = sIn[3 * t + 1], z = sIn[3 * t + 2];
    int i = (idx < N) ? idx : idx - N;

    unsigned short xh = bf16_rn(x), yh = bf16_rn(y), zh = bf16_rn(z);
    unsigned short xl = bf16_rn(x - bf16f(xh));
    unsigned short yl = bf16_rn(y - bf16f(yh));
    unsigned short zl = bf16_rn(z - bf16f(zh));
    float s = __builtin_fmaf(x, x, __builtin_fmaf(y, y, z * z));
    unsigned short sh = bf16_rn(s), sl = bf16_rn(s - bf16f(sh));
    // -2*h is exact in bf16 (scale by 2 + sign flip)
    unsigned short m2xh = bf16_rn(-2.0f * bf16f(xh)), m2xl = bf16_rn(-2.0f * bf16f(xl));
    unsigned short m2yh = bf16_rn(-2.0f * bf16f(yh)), m2yl = bf16_rn(-2.0f * bf16f(yl));
    unsigned short m2zh = bf16_rn(-2.0f * bf16f(zh)), m2zl = bf16_rn(-2.0f * bf16f(zl));
    const unsigned short one = 0x3F80;

    // k:      0     1     2     3     4     5     6     7     8     9    10    11   12 13  14  15
    unsigned short q[16] = { m2xh, m2xh, m2xl, m2xl, m2yh, m2yh, m2yl, m2yl,
                             m2zh, m2zh, m2zl, m2zl, sh, sl, one, one };
    unsigned short r[16] = { xh, xl, xh, xl, yh, yl, yh, yl,
                             zh, zl, zh, zl, one, one, sh, sl };
    // sum_k q[k]*r'[k] = -2(a.b') + |a|^2 + |b'|^2 = d^2

    uint4* Qa = frags + ((idx < N) ? 0 : FRAG_U4);
    uint4* Ra = frags + 2 * FRAG_U4 + ((idx < N) ? 0 : FRAG_U4);
    int tt = i >> 5, rr = i & 31;
    Qa[tt * 64 +      rr] = pack8(q);
    Qa[tt * 64 + 32 + rr] = pack8(q + 8);
    Ra[tt * 64 +      rr] = pack8(r);
    Ra[tt * 64 + 32 + rr] = pack8(r + 8);
}

__global__ void __launch_bounds__(TPB, 2) chamfer_mfma(const uint4* __restrict__ frags,
                                                       int* __restrict__ minbuf,
                                                       int* __restrict__ done,
                                                       float* __restrict__ out)
{
    int lane = threadIdx.x & 63;
    int w    = (int)(threadIdx.x >> 6);
    int wid  = blockIdx.x * 4 + w;
    int strip  = wid & (NSTRIP - 1);          // 4 waves/block = adjacent strips,
    int jsplit = (wid >> 7) & (NJSPLIT - 1);  // same jsplit -> B-stream L1-shared
    int pass   = wid >> 10;                   // 0: queries=p_hat, 1: queries=p

    const uint4* Q = frags + (pass ? FRAG_U4 : 0);               // queries (A rows)
    const uint4* R = frags + 2 * FRAG_U4 + (pass ? 0 : FRAG_U4); // refs (B cols)

    bf16x8 A[MT];
#pragma unroll
    for (int m = 0; m < MT; ++m)
        A[m] = __builtin_bit_cast(bf16x8, Q[(strip * MT + m) * 64 + lane]);

    fx16 zf;
#pragma unroll
    for (int r2 = 0; r2 < 16; ++r2) zf[r2] = 0.0f;
    fx16 rmin[MT];
#pragma unroll
    for (int m = 0; m < MT; ++m)
#pragma unroll
        for (int r2 = 0; r2 < 16; ++r2) rmin[m][r2] = __builtin_inff();

    const uint4* Rj = R + jsplit * (JW * 64) + lane;
    // EXACT round-6 K-loop (42.5us best): 2-tile pair steps, 1-pair-deep
    // prefetch with WRAP indexing (never reads outside this jsplit's range).
    uint4 ca = Rj[0];
    uint4 cb = Rj[64];
    for (int jj = 0; jj < JW; jj += 2) {
        int n2 = (jj + 2 < JW) ? (jj + 2) : 0;
        int n3 = (jj + 2 < JW) ? (jj + 3) : 1;
        uint4 na = Rj[n2 * 64];
        uint4 nb = Rj[n3 * 64];
        bf16x8 Ba = __builtin_bit_cast(bf16x8, ca);
        bf16x8 Bb = __builtin_bit_cast(bf16x8, cb);
#pragma unroll
        for (int m = 0; m < MT; ++m) {
            fx16 da = __builtin_amdgcn_mfma_f32_32x32x16_bf16(A[m], Ba, zf, 0, 0, 0);
            fx16 db = __builtin_amdgcn_mfma_f32_32x32x16_bf16(A[m], Bb, zf, 0, 0, 0);
#pragma unroll
            for (int r2 = 0; r2 < 16; ++r2) {
                // pure fminf (exact; clang may fuse to v_min3) — NO inline asm
                rmin[m][r2] = fminf(rmin[m][r2], fminf(da[r2], db[r2]));
            }
        }
        ca = na; cb = nb;
    }

    // VERIFIED epilogue: min over cols via lane shuffles within each 32-half;
    // publish rows by the m74/m101 formula. Insensitive to column permutation.
    int rowbase = pass * N + strip * (MT * 32) + 4 * (lane >> 5);
#pragma unroll
    for (int m = 0; m < MT; ++m) {
#pragma unroll
        for (int r2 = 0; r2 < 16; ++r2) {
            float v = rmin[m][r2];
            v = fminf(v, __shfl_xor(v, 1));
            v = fminf(v, __shfl_xor(v, 2));
            v = fminf(v, __shfl_xor(v, 4));
            v = fminf(v, __shfl_xor(v, 8));
            v = fminf(v, __shfl_xor(v, 16));
            if ((lane & 31) == 0) {
                int row = rowbase + m * 32 + (r2 & 3) + 8 * (r2 >> 2);
                atomicMin(&minbuf[row], __float_as_int(fmaxf(v, 0.0f)));
            }
        }
    }

    // ---- last-block final reduce (replaces reduce_kernel launch) ----
    __threadfence();                          // release: my atomicMins visible
    __shared__ int isLast;
    if (threadIdx.x == 0) {
        int old = atomicAdd(done, 1);         // device-scope by default
        isLast = (old == NBLK_MFMA - 1);
    }
    __syncthreads();                          // isLast uniform across block
    if (isLast) {
        __threadfence();                      // acquire side
        float s = 0.0f;
        // agent-scope atomic loads bypass L1 -> no stale lines (G16);
        // lane i reads minbuf[i + 256k]: coalesced 256B/wave per step.
        for (int k = (int)threadIdx.x; k < 2 * N; k += TPB) {
            int bits = __hip_atomic_load(&minbuf[k], __ATOMIC_RELAXED,
                                         __HIP_MEMORY_SCOPE_AGENT);
            s += __int_as_float(bits);
        }
        for (int off = 32; off > 0; off >>= 1) s += __shfl_down(s, off, 64);
        __shared__ float partial[TPB / 64];
        if ((threadIdx.x & 63) == 0) partial[threadIdx.x >> 6] = s;
        __syncthreads();
        if (threadIdx.x == 0) {
            float tsum = 0.0f;
            for (int q = 0; q < TPB / 64; ++q) tsum += partial[q];
            out[0] = tsum / (float)N;
        }
    }
}

// ================= fallback fp32 path (ws too small) =================
#define OQPT 4
#define OQTILE (TPB * OQPT)
#define ONQT (N / OQTILE)
#define OSPLIT 64
#define OCHUNK (N / OSPLIT)
#define OGRID (2 * OSPLIT * ONQT)

__global__ void pack_old(const float* __restrict__ p_hat, const float* __restrict__ p,
                         float4* __restrict__ q4, int* __restrict__ minbuf) {
    int idx = blockIdx.x * blockDim.x + threadIdx.x;
    if (idx >= 2 * N) return;
    const float* src = (idx < N) ? p_hat : p;
    int k = (idx < N) ? idx : idx - N;
    float x = src[3*k+0], y = src[3*k+1], z = src[3*k+2];
    q4[idx] = make_float4(x, y, z, x*x + y*y + z*z);
    minbuf[idx] = INF_BITS;
}

__global__ void __launch_bounds__(TPB) chamfer_old(const float4* __restrict__ q4,
                                                   int* __restrict__ minbuf) {
    int b = blockIdx.x;
    int dir = b & 1;
    int rest = b >> 1;
    int jc = rest & (OSPLIT - 1);
    int qt = rest >> 6;
    const float4* __restrict__ qp = q4 + (dir ? N : 0);
    const float4* __restrict__ rp = q4 + (dir ? 0 : N);
    int ibase = qt * OQTILE + (int)threadIdx.x;
    float m2x[OQPT], m2y[OQPT], m2z[OQPT], qw[OQPT], vmin[OQPT];
#pragma unroll
    for (int q = 0; q < OQPT; ++q) {
        float4 qq = qp[ibase + q * TPB];
        m2x[q] = -2.0f * qq.x; m2y[q] = -2.0f * qq.y; m2z[q] = -2.0f * qq.z;
        qw[q] = qq.w; vmin[q] = __builtin_inff();
    }
    int j0 = jc * OCHUNK;
    float4 ra = rp[j0];
    float4 rb = rp[j0 + 1];
#pragma unroll 2
    for (int j = j0; j < j0 + OCHUNK; j += 2) {
        float4 na = rp[j + 2];
        float4 nb = rp[j + 3];
        float raw = ra.w, rbw = rb.w;
#pragma unroll
        for (int q = 0; q < OQPT; ++q) {
            float ta = __builtin_fmaf(ra.x, m2x[q],
                       __builtin_fmaf(ra.y, m2y[q],
                       __builtin_fmaf(ra.z, m2z[q], raw)));
            float tb = __builtin_fmaf(rb.x, m2x[q],
                       __builtin_fmaf(rb.y, m2y[q],
                       __builtin_fmaf(rb.z, m2z[q], rbw)));
            vmin[q] = fminf(vmin[q], fminf(ta, tb));
        }
        ra = na; rb = nb;
    }
#pragma unroll
    for (int q = 0; q < OQPT; ++q) {
        float m = fmaxf(vmin[q] + qw[q], 0.0f);
        atomicMin(&minbuf[dir * N + ibase + q * TPB], __float_as_int(m));
    }
}

__global__ void __launch_bounds__(1024) reduce_kernel(const int* __restrict__ minbuf,
                                                      float* __restrict__ out) {
    const int4* mb4 = (const int4*)minbuf;  // 2N/4 = 8192 int4
    float s = 0.0f;
#pragma unroll
    for (int k = 0; k < (2 * N / 4) / 1024; ++k) {
        int4 v = mb4[k * 1024 + threadIdx.x];
        s += __int_as_float(v.x) + __int_as_float(v.y) +
             __int_as_float(v.z) + __int_as_float(v.w);
    }
    for (int off = 32; off > 0; off >>= 1) s += __shfl_down(s, off, 64);
    __shared__ float partial[1024 / 64];
    int lane = threadIdx.x & 63;
    int wid  = threadIdx.x >> 6;
    if (lane == 0) partial[wid] = s;
    __syncthreads();
    if (threadIdx.x == 0) {
        float t = 0.0f;
        for (int w = 0; w < 1024 / 64; ++w) t += partial[w];
        out[0] = t / (float)N;
    }
}

// ================= launcher =================
extern "C" void kernel_launch(void* const* d_in, const int* in_sizes, int n_in,
                              void* d_out, int out_size, void* d_ws, size_t ws_size,
                              hipStream_t stream) {
    const float* p_hat = (const float*)d_in[0];
    const float* p     = (const float*)d_in[1];
    float* out = (float*)d_out;
    if (ws_size >= WS_NEED_MFMA) {
        uint4* frags = (uint4*)d_ws;
        int* minbuf  = (int*)((char*)d_ws + 4ull * FRAG_U4 * sizeof(uint4));
        int* done    = minbuf + 2 * N;
        pack_mfma<<<(2 * N) / TPB, TPB, 0, stream>>>(p_hat, p, frags, minbuf, done);
        chamfer_mfma<<<NBLK_MFMA, TPB, 0, stream>>>(frags, minbuf, done, out);
    } else {
        float4* q4  = (float4*)d_ws;
        int* minbuf = (int*)((char*)d_ws + 2 * N * sizeof(float4));
        pack_old<<<(2 * N + TPB - 1) / TPB, TPB, 0, stream>>>(p_hat, p, q4, minbuf);
        chamfer_old<<<OGRID, TPB, 0, stream>>>(q4, minbuf);
        reduce_kernel<<<1, 1024, 0, stream>>>(minbuf, out);
    }
}

// Round 11
// 104.569 us; speedup vs baseline: 1.3860x; 1.3860x over previous
//
#include <hip/hip_runtime.h>

#define N 16384
#define TPB 256
#define INF_BITS 0x7F800000

// ================= MFMA path =================
// d^2 tile = 32x32 via v_mfma_f32_32x32x16_bf16, K=16 slots encode
// -2 a.b (12 slots, hi/lo bf16 split, products exact) + |a|^2 + |b|^2 (4 slots).
// Geometry: queries on A rows (resident), refs streamed on B cols; reduction =
// lane-shuffle min over cols + row-formula publish (rounds 1/6-10 VERIFIED).
// LEDGER (do not retry without new evidence):
//  - inline asm on MFMA results: BROKEN (r2,r3 failed; r1,r6-10 pure-fminf pass)
//  - occupancy x2 (r7): regressed. register 8-bank pipeline (r8): regressed.
//  - LDS double-buffer staging (r9): regressed. reduce fused via last-block +
//    threadfence (r10): catastrophic (device fence = L2 writeback x512 blocks).
//  - total-minus-chamfer ~50us is harness-fixed (r10 proved: -1 launch = no gain).
// THIS ROUND: MT 4->8 on the EXACT round-6 loop — halves B-load count (the
// measured stall source), doubles issue work per prefetch slot. Same 2048
// waves / 512 blocks / 2 per CU. Math bit-identical.
#define NT32 (N / 32)                 // 512 tiles per side
#define MT 8                          // query tiles per wave (A frags, resident)
#define NSTRIP (NT32 / MT)            // 64
#define NJSPLIT 16                    // ref-column splits per pass
#define JW (NT32 / NJSPLIT)           // 32 ref tiles per wave
#define NWAVES (2 * NSTRIP * NJSPLIT) // 2048 (same as round 6)
#define NBLK_MFMA (NWAVES / 4)        // 512 blocks = 2/CU (same as round 6)
#define FRAG_U4 (NT32 * 64)           // uint4 per fragment array (512 KB)
#define WS_NEED_MFMA (4ull * FRAG_U4 * sizeof(uint4) + 2ull * N * sizeof(int))

using bf16x8 = __attribute__((ext_vector_type(8))) short;
using fx16   = __attribute__((ext_vector_type(16))) float;

__device__ __forceinline__ unsigned short bf16_rn(float f) {
    unsigned u = __float_as_uint(f);
    u += 0x7FFFu + ((u >> 16) & 1u);        // round-to-nearest-even
    return (unsigned short)(u >> 16);
}
__device__ __forceinline__ float bf16f(unsigned short h) {
    return __uint_as_float(((unsigned)h) << 16);
}
__device__ __forceinline__ uint4 pack8(const unsigned short* a) {
    return make_uint4((unsigned)a[0] | ((unsigned)a[1] << 16),
                      (unsigned)a[2] | ((unsigned)a[3] << 16),
                      (unsigned)a[4] | ((unsigned)a[5] << 16),
                      (unsigned)a[6] | ((unsigned)a[7] << 16));
}

// frags layout (uint4 units): [Q0 | Q1 | R0 | R1], each FRAG_U4.
// Tile t, lane l holds 8 bf16 = k-slots (l>>5)*8..+7 for point (t*32 + (l&31)).
// A and B use the SAME (lane,elem)->k packing, so the MFMA pairing is correct
// regardless of the HW's internal k mapping (verified: rounds 1/6-10).
__global__ void pack_mfma(const float* __restrict__ p_hat, const float* __restrict__ p,
                          uint4* __restrict__ frags, int* __restrict__ minbuf)
{
    int idx = blockIdx.x * blockDim.x + threadIdx.x;
    if (idx >= 2 * N) return;
    minbuf[idx] = INF_BITS;
    const float* src = (idx < N) ? p_hat : p;
    int i = (idx < N) ? idx : idx - N;
    float x = src[3*i+0], y = src[3*i+1], z = src[3*i+2];

    unsigned short xh = bf16_rn(x), yh = bf16_rn(y), zh = bf16_rn(z);
    unsigned short xl = bf16_rn(x - bf16f(xh));
    unsigned short yl = bf16_rn(y - bf16f(yh));
    unsigned short zl = bf16_rn(z - bf16f(zh));
    float s = __builtin_fmaf(x, x, __builtin_fmaf(y, y, z * z));
    unsigned short sh = bf16_rn(s), sl = bf16_rn(s - bf16f(sh));
    // -2*h is exact in bf16 (scale by 2 + sign flip)
    unsigned short m2xh = bf16_rn(-2.0f * bf16f(xh)), m2xl = bf16_rn(-2.0f * bf16f(xl));
    unsigned short m2yh = bf16_rn(-2.0f * bf16f(yh)), m2yl = bf16_rn(-2.0f * bf16f(yl));
    unsigned short m2zh = bf16_rn(-2.0f * bf16f(zh)), m2zl = bf16_rn(-2.0f * bf16f(zl));
    const unsigned short one = 0x3F80;

    // k:      0     1     2     3     4     5     6     7     8     9    10    11   12 13  14  15
    unsigned short q[16] = { m2xh, m2xh, m2xl, m2xl, m2yh, m2yh, m2yl, m2yl,
                             m2zh, m2zh, m2zl, m2zl, sh, sl, one, one };
    unsigned short r[16] = { xh, xl, xh, xl, yh, yl, yh, yl,
                             zh, zl, zh, zl, one, one, sh, sl };
    // sum_k q[k]*r'[k] = -2(a.b') + |a|^2 + |b'|^2 = d^2

    uint4* Qa = frags + ((idx < N) ? 0 : FRAG_U4);
    uint4* Ra = frags + 2 * FRAG_U4 + ((idx < N) ? 0 : FRAG_U4);
    int t = i >> 5, rr = i & 31;
    Qa[t * 64 +      rr] = pack8(q);
    Qa[t * 64 + 32 + rr] = pack8(q + 8);
    Ra[t * 64 +      rr] = pack8(r);
    Ra[t * 64 + 32 + rr] = pack8(r + 8);
}

// launch_bounds(256, 2): 256-VGPR budget. Expected ~210 VGPR (rmin 128 + A 32
// + d 32 + addressing) -> 2 waves/SIMD, which matches the grid's 8 waves/CU.
__global__ void __launch_bounds__(TPB, 2) chamfer_mfma(const uint4* __restrict__ frags,
                                                       int* __restrict__ minbuf)
{
    int lane = threadIdx.x & 63;
    int wid  = blockIdx.x * 4 + (int)(threadIdx.x >> 6);
    int strip  = wid & (NSTRIP - 1);          // 4 waves/block = adjacent strips,
    int jsplit = (wid >> 6) & (NJSPLIT - 1);  // same jsplit -> B-stream L1-shared
    int pass   = wid >> 10;                   // 0: queries=p_hat, 1: queries=p

    const uint4* Q = frags + (pass ? FRAG_U4 : 0);               // queries (A rows)
    const uint4* R = frags + 2 * FRAG_U4 + (pass ? 0 : FRAG_U4); // refs (B cols)

    bf16x8 A[MT];
#pragma unroll
    for (int m = 0; m < MT; ++m)
        A[m] = __builtin_bit_cast(bf16x8, Q[(strip * MT + m) * 64 + lane]);

    fx16 zf;
#pragma unroll
    for (int r2 = 0; r2 < 16; ++r2) zf[r2] = 0.0f;
    fx16 rmin[MT];
#pragma unroll
    for (int m = 0; m < MT; ++m)
#pragma unroll
        for (int r2 = 0; r2 < 16; ++r2) rmin[m][r2] = __builtin_inff();

    const uint4* Rj = R + jsplit * (JW * 64) + lane;
    // EXACT round-6 K-loop structure: 2-tile pair steps, 1-pair-deep prefetch
    // with WRAP indexing (never reads outside this jsplit's range).
    uint4 ca = Rj[0];
    uint4 cb = Rj[64];
    for (int jj = 0; jj < JW; jj += 2) {
        int n2 = (jj + 2 < JW) ? (jj + 2) : 0;
        int n3 = (jj + 2 < JW) ? (jj + 3) : 1;
        uint4 na = Rj[n2 * 64];
        uint4 nb = Rj[n3 * 64];
        bf16x8 Ba = __builtin_bit_cast(bf16x8, ca);
        bf16x8 Bb = __builtin_bit_cast(bf16x8, cb);
#pragma unroll
        for (int m = 0; m < MT; ++m) {
            fx16 da = __builtin_amdgcn_mfma_f32_32x32x16_bf16(A[m], Ba, zf, 0, 0, 0);
            fx16 db = __builtin_amdgcn_mfma_f32_32x32x16_bf16(A[m], Bb, zf, 0, 0, 0);
#pragma unroll
            for (int r2 = 0; r2 < 16; ++r2) {
                // pure fminf (exact; clang may fuse to v_min3) — NO inline asm
                rmin[m][r2] = fminf(rmin[m][r2], fminf(da[r2], db[r2]));
            }
        }
        ca = na; cb = nb;
    }

    // VERIFIED epilogue: min over cols via lane shuffles within each 32-half;
    // publish rows by the m74/m101 formula. Insensitive to column permutation.
    int rowbase = pass * N + strip * (MT * 32) + 4 * (lane >> 5);
#pragma unroll
    for (int m = 0; m < MT; ++m) {
#pragma unroll
        for (int r2 = 0; r2 < 16; ++r2) {
            float v = rmin[m][r2];
            v = fminf(v, __shfl_xor(v, 1));
            v = fminf(v, __shfl_xor(v, 2));
            v = fminf(v, __shfl_xor(v, 4));
            v = fminf(v, __shfl_xor(v, 8));
            v = fminf(v, __shfl_xor(v, 16));
            if ((lane & 31) == 0) {
                int row = rowbase + m * 32 + (r2 & 3) + 8 * (r2 >> 2);
                atomicMin(&minbuf[row], __float_as_int(fmaxf(v, 0.0f)));
            }
        }
    }
}

// ================= shared reduce =================
__global__ void __launch_bounds__(1024) reduce_kernel(const int* __restrict__ minbuf,
                                                      float* __restrict__ out) {
    const int4* mb4 = (const int4*)minbuf;  // 2N/4 = 8192 int4
    float s = 0.0f;
#pragma unroll
    for (int k = 0; k < (2 * N / 4) / 1024; ++k) {
        int4 v = mb4[k * 1024 + threadIdx.x];
        s += __int_as_float(v.x) + __int_as_float(v.y) +
             __int_as_float(v.z) + __int_as_float(v.w);
    }
    for (int off = 32; off > 0; off >>= 1) s += __shfl_down(s, off, 64);
    __shared__ float partial[1024 / 64];
    int lane = threadIdx.x & 63;
    int wid  = threadIdx.x >> 6;
    if (lane == 0) partial[wid] = s;
    __syncthreads();
    if (threadIdx.x == 0) {
        float t = 0.0f;
        for (int w = 0; w < 1024 / 64; ++w) t += partial[w];
        out[0] = t / (float)N;
    }
}

// ================= fallback fp32 path (ws too small) =================
#define OQPT 4
#define OQTILE (TPB * OQPT)
#define ONQT (N / OQTILE)
#define OSPLIT 64
#define OCHUNK (N / OSPLIT)
#define OGRID (2 * OSPLIT * ONQT)

__global__ void pack_old(const float* __restrict__ p_hat, const float* __restrict__ p,
                         float4* __restrict__ q4, int* __restrict__ minbuf) {
    int idx = blockIdx.x * blockDim.x + threadIdx.x;
    if (idx >= 2 * N) return;
    const float* src = (idx < N) ? p_hat : p;
    int k = (idx < N) ? idx : idx - N;
    float x = src[3*k+0], y = src[3*k+1], z = src[3*k+2];
    q4[idx] = make_float4(x, y, z, x*x + y*y + z*z);
    minbuf[idx] = INF_BITS;
}

__global__ void __launch_bounds__(TPB) chamfer_old(const float4* __restrict__ q4,
                                                   int* __restrict__ minbuf) {
    int b = blockIdx.x;
    int dir = b & 1;
    int rest = b >> 1;
    int jc = rest & (OSPLIT - 1);
    int qt = rest >> 6;
    const float4* __restrict__ qp = q4 + (dir ? N : 0);
    const float4* __restrict__ rp = q4 + (dir ? 0 : N);
    int ibase = qt * OQTILE + (int)threadIdx.x;
    float m2x[OQPT], m2y[OQPT], m2z[OQPT], qw[OQPT], vmin[OQPT];
#pragma unroll
    for (int q = 0; q < OQPT; ++q) {
        float4 qq = qp[ibase + q * TPB];
        m2x[q] = -2.0f * qq.x; m2y[q] = -2.0f * qq.y; m2z[q] = -2.0f * qq.z;
        qw[q] = qq.w; vmin[q] = __builtin_inff();
    }
    int j0 = jc * OCHUNK;
    float4 ra = rp[j0];
    float4 rb = rp[j0 + 1];
#pragma unroll 2
    for (int j = j0; j < j0 + OCHUNK; j += 2) {
        float4 na = rp[j + 2];
        float4 nb = rp[j + 3];
        float raw = ra.w, rbw = rb.w;
#pragma unroll
        for (int q = 0; q < OQPT; ++q) {
            float ta = __builtin_fmaf(ra.x, m2x[q],
                       __builtin_fmaf(ra.y, m2y[q],
                       __builtin_fmaf(ra.z, m2z[q], raw)));
            float tb = __builtin_fmaf(rb.x, m2x[q],
                       __builtin_fmaf(rb.y, m2y[q],
                       __builtin_fmaf(rb.z, m2z[q], rbw)));
            vmin[q] = fminf(vmin[q], fminf(ta, tb));
        }
        ra = na; rb = nb;
    }
#pragma unroll
    for (int q = 0; q < OQPT; ++q) {
        float m = fmaxf(vmin[q] + qw[q], 0.0f);
        atomicMin(&minbuf[dir * N + ibase + q * TPB], __float_as_int(m));
    }
}

// ================= launcher =================
extern "C" void kernel_launch(void* const* d_in, const int* in_sizes, int n_in,
                              void* d_out, int out_size, void* d_ws, size_t ws_size,
                              hipStream_t stream) {
    const float* p_hat = (const float*)d_in[0];
    const float* p     = (const float*)d_in[1];
    float* out = (float*)d_out;
    if (ws_size >= WS_NEED_MFMA) {
        uint4* frags = (uint4*)d_ws;
        int* minbuf  = (int*)((char*)d_ws + 4ull * FRAG_U4 * sizeof(uint4));
        pack_mfma<<<(2 * N + TPB - 1) / TPB, TPB, 0, stream>>>(p_hat, p, frags, minbuf);
        chamfer_mfma<<<NBLK_MFMA, TPB, 0, stream>>>(frags, minbuf);
        reduce_kernel<<<1, 1024, 0, stream>>>(minbuf, out);
    } else {
        float4* q4  = (float4*)d_ws;
        int* minbuf = (int*)((char*)d_ws + 2 * N * sizeof(float4));
        pack_old<<<(2 * N + TPB - 1) / TPB, TPB, 0, stream>>>(p_hat, p, q4, minbuf);
        chamfer_old<<<OGRID, TPB, 0, stream>>>(q4, minbuf);
        reduce_kernel<<<1, 1024, 0, stream>>>(minbuf, out);
    }
}

// Round 12
// 89.341 us; speedup vs baseline: 1.6222x; 1.1705x over previous
//
#include <hip/hip_runtime.h>

#define N 16384
#define TPB 256
#define INF_BITS 0x7F800000

// ================= MFMA path =================
// d^2 tile = 32x32 via v_mfma_f32_32x32x16_bf16, K=16 slots encode
// -2 a.b (12 slots, hi/lo bf16 split, products exact) + |a|^2 + |b|^2 (4 slots).
// Geometry: queries on A rows (resident), refs streamed on B cols; reduction =
// lane-shuffle min over cols + row-formula publish (rounds 1/6-11 VERIFIED).
// LEDGER (do not retry without new evidence):
//  - inline asm on MFMA results: BROKEN (r2,r3). occupancy x2 (r7): regressed.
//  - 8-bank reload-after-consume pipeline (r8): VALU bloat, regressed.
//  - LDS double-buffer staging (r9): regressed. fused reduce+fence (r10): bad.
//  - MT=8 (r11): VGPR spill (128 cap, +13MB scratch HBM traffic).
//  - total-minus-chamfer ~50us is harness-fixed (r10: -1 launch = no gain).
// THIS ROUND (last K-loop experiment): 4-deep rolling prefetch on the EXACT
// r6 structure — MLP 2->4, +8 VGPR, +16 v_mov/iter. Consumption order
// unchanged -> bit-identical result.
#define NT32 (N / 32)                 // 512 tiles per side
#define MT 4                          // query tiles per wave (A frags, resident)
#define NSTRIP (NT32 / MT)            // 128
#define NJSPLIT 8                     // ref-column splits per pass
#define JW (NT32 / NJSPLIT)           // 64 ref tiles per wave
#define NWAVES (2 * NSTRIP * NJSPLIT) // 2048
#define NBLK_MFMA (NWAVES / 4)        // 512 blocks = 2/CU
#define FRAG_U4 (NT32 * 64)           // uint4 per fragment array (512 KB)
#define WS_NEED_MFMA (4ull * FRAG_U4 * sizeof(uint4) + 2ull * N * sizeof(int))

using bf16x8 = __attribute__((ext_vector_type(8))) short;
using fx16   = __attribute__((ext_vector_type(16))) float;

__device__ __forceinline__ unsigned short bf16_rn(float f) {
    unsigned u = __float_as_uint(f);
    u += 0x7FFFu + ((u >> 16) & 1u);        // round-to-nearest-even
    return (unsigned short)(u >> 16);
}
__device__ __forceinline__ float bf16f(unsigned short h) {
    return __uint_as_float(((unsigned)h) << 16);
}
__device__ __forceinline__ uint4 pack8(const unsigned short* a) {
    return make_uint4((unsigned)a[0] | ((unsigned)a[1] << 16),
                      (unsigned)a[2] | ((unsigned)a[3] << 16),
                      (unsigned)a[4] | ((unsigned)a[5] << 16),
                      (unsigned)a[6] | ((unsigned)a[7] << 16));
}

// frags layout (uint4 units): [Q0 | Q1 | R0 | R1], each FRAG_U4.
// Tile t, lane l holds 8 bf16 = k-slots (l>>5)*8..+7 for point (t*32 + (l&31)).
// A and B use the SAME (lane,elem)->k packing, so the MFMA pairing is correct
// regardless of the HW's internal k mapping (verified: rounds 1/6-11).
__global__ void pack_mfma(const float* __restrict__ p_hat, const float* __restrict__ p,
                          uint4* __restrict__ frags, int* __restrict__ minbuf)
{
    int idx = blockIdx.x * blockDim.x + threadIdx.x;
    if (idx >= 2 * N) return;
    minbuf[idx] = INF_BITS;
    const float* src = (idx < N) ? p_hat : p;
    int i = (idx < N) ? idx : idx - N;
    float x = src[3*i+0], y = src[3*i+1], z = src[3*i+2];

    unsigned short xh = bf16_rn(x), yh = bf16_rn(y), zh = bf16_rn(z);
    unsigned short xl = bf16_rn(x - bf16f(xh));
    unsigned short yl = bf16_rn(y - bf16f(yh));
    unsigned short zl = bf16_rn(z - bf16f(zh));
    float s = __builtin_fmaf(x, x, __builtin_fmaf(y, y, z * z));
    unsigned short sh = bf16_rn(s), sl = bf16_rn(s - bf16f(sh));
    // -2*h is exact in bf16 (scale by 2 + sign flip)
    unsigned short m2xh = bf16_rn(-2.0f * bf16f(xh)), m2xl = bf16_rn(-2.0f * bf16f(xl));
    unsigned short m2yh = bf16_rn(-2.0f * bf16f(yh)), m2yl = bf16_rn(-2.0f * bf16f(yl));
    unsigned short m2zh = bf16_rn(-2.0f * bf16f(zh)), m2zl = bf16_rn(-2.0f * bf16f(zl));
    const unsigned short one = 0x3F80;

    // k:      0     1     2     3     4     5     6     7     8     9    10    11   12 13  14  15
    unsigned short q[16] = { m2xh, m2xh, m2xl, m2xl, m2yh, m2yh, m2yl, m2yl,
                             m2zh, m2zh, m2zl, m2zl, sh, sl, one, one };
    unsigned short r[16] = { xh, xl, xh, xl, yh, yl, yh, yl,
                             zh, zl, zh, zl, one, one, sh, sl };
    // sum_k q[k]*r'[k] = -2(a.b') + |a|^2 + |b'|^2 = d^2

    uint4* Qa = frags + ((idx < N) ? 0 : FRAG_U4);
    uint4* Ra = frags + 2 * FRAG_U4 + ((idx < N) ? 0 : FRAG_U4);
    int t = i >> 5, rr = i & 31;
    Qa[t * 64 +      rr] = pack8(q);
    Qa[t * 64 + 32 + rr] = pack8(q + 8);
    Ra[t * 64 +      rr] = pack8(r);
    Ra[t * 64 + 32 + rr] = pack8(r + 8);
}

__global__ void __launch_bounds__(TPB, 2) chamfer_mfma(const uint4* __restrict__ frags,
                                                       int* __restrict__ minbuf)
{
    int lane = threadIdx.x & 63;
    int wid  = blockIdx.x * 4 + (int)(threadIdx.x >> 6);
    int strip  = wid & (NSTRIP - 1);          // 4 waves/block = adjacent strips,
    int jsplit = (wid >> 7) & (NJSPLIT - 1);  // same jsplit -> B-stream L1-shared
    int pass   = wid >> 10;                   // 0: queries=p_hat, 1: queries=p

    const uint4* Q = frags + (pass ? FRAG_U4 : 0);               // queries (A rows)
    const uint4* R = frags + 2 * FRAG_U4 + (pass ? 0 : FRAG_U4); // refs (B cols)

    bf16x8 A[MT];
#pragma unroll
    for (int m = 0; m < MT; ++m)
        A[m] = __builtin_bit_cast(bf16x8, Q[(strip * MT + m) * 64 + lane]);

    fx16 zf;
#pragma unroll
    for (int r2 = 0; r2 < 16; ++r2) zf[r2] = 0.0f;
    fx16 rmin[MT];
#pragma unroll
    for (int m = 0; m < MT; ++m)
#pragma unroll
        for (int r2 = 0; r2 < 16; ++r2) rmin[m][r2] = __builtin_inff();

    const uint4* Rj = R + jsplit * (JW * 64) + lane;
    // 4-deep rolling prefetch (r6 was 2-deep): loads issued 2 iterations ahead
    // of consumption (~840cy slack, 4 outstanding/wave). WRAP indexing keeps
    // every read inside this jsplit's range (wrapped values dead). Consumption
    // order is tile jj, jj+1 per group — identical to r6 -> bit-identical.
    uint4 c0 = Rj[0 * 64];
    uint4 c1 = Rj[1 * 64];
    uint4 c2 = Rj[2 * 64];
    uint4 c3 = Rj[3 * 64];
    for (int jj = 0; jj < JW; jj += 2) {
        int n4 = (jj + 4 < JW) ? (jj + 4) : 0;
        int n5 = (jj + 4 < JW) ? (jj + 5) : 1;
        uint4 p0 = Rj[n4 * 64];
        uint4 p1 = Rj[n5 * 64];
        bf16x8 Ba = __builtin_bit_cast(bf16x8, c0);
        bf16x8 Bb = __builtin_bit_cast(bf16x8, c1);
#pragma unroll
        for (int m = 0; m < MT; ++m) {
            fx16 da = __builtin_amdgcn_mfma_f32_32x32x16_bf16(A[m], Ba, zf, 0, 0, 0);
            fx16 db = __builtin_amdgcn_mfma_f32_32x32x16_bf16(A[m], Bb, zf, 0, 0, 0);
#pragma unroll
            for (int r2 = 0; r2 < 16; ++r2) {
                // pure fminf (exact; clang may fuse to v_min3) — NO inline asm
                rmin[m][r2] = fminf(rmin[m][r2], fminf(da[r2], db[r2]));
            }
        }
        c0 = c2; c1 = c3; c2 = p0; c3 = p1;
    }

    // VERIFIED epilogue: min over cols via lane shuffles within each 32-half;
    // publish rows by the m74/m101 formula. Insensitive to column permutation.
    int rowbase = pass * N + strip * (MT * 32) + 4 * (lane >> 5);
#pragma unroll
    for (int m = 0; m < MT; ++m) {
#pragma unroll
        for (int r2 = 0; r2 < 16; ++r2) {
            float v = rmin[m][r2];
            v = fminf(v, __shfl_xor(v, 1));
            v = fminf(v, __shfl_xor(v, 2));
            v = fminf(v, __shfl_xor(v, 4));
            v = fminf(v, __shfl_xor(v, 8));
            v = fminf(v, __shfl_xor(v, 16));
            if ((lane & 31) == 0) {
                int row = rowbase + m * 32 + (r2 & 3) + 8 * (r2 >> 2);
                atomicMin(&minbuf[row], __float_as_int(fmaxf(v, 0.0f)));
            }
        }
    }
}

// ================= shared reduce =================
__global__ void __launch_bounds__(1024) reduce_kernel(const int* __restrict__ minbuf,
                                                      float* __restrict__ out) {
    const int4* mb4 = (const int4*)minbuf;  // 2N/4 = 8192 int4
    float s = 0.0f;
#pragma unroll
    for (int k = 0; k < (2 * N / 4) / 1024; ++k) {
        int4 v = mb4[k * 1024 + threadIdx.x];
        s += __int_as_float(v.x) + __int_as_float(v.y) +
             __int_as_float(v.z) + __int_as_float(v.w);
    }
    for (int off = 32; off > 0; off >>= 1) s += __shfl_down(s, off, 64);
    __shared__ float partial[1024 / 64];
    int lane = threadIdx.x & 63;
    int wid  = threadIdx.x >> 6;
    if (lane == 0) partial[wid] = s;
    __syncthreads();
    if (threadIdx.x == 0) {
        float t = 0.0f;
        for (int w = 0; w < 1024 / 64; ++w) t += partial[w];
        out[0] = t / (float)N;
    }
}

// ================= fallback fp32 path (ws too small) =================
#define OQPT 4
#define OQTILE (TPB * OQPT)
#define ONQT (N / OQTILE)
#define OSPLIT 64
#define OCHUNK (N / OSPLIT)
#define OGRID (2 * OSPLIT * ONQT)

__global__ void pack_old(const float* __restrict__ p_hat, const float* __restrict__ p,
                         float4* __restrict__ q4, int* __restrict__ minbuf) {
    int idx = blockIdx.x * blockDim.x + threadIdx.x;
    if (idx >= 2 * N) return;
    const float* src = (idx < N) ? p_hat : p;
    int k = (idx < N) ? idx : idx - N;
    float x = src[3*k+0], y = src[3*k+1], z = src[3*k+2];
    q4[idx] = make_float4(x, y, z, x*x + y*y + z*z);
    minbuf[idx] = INF_BITS;
}

__global__ void __launch_bounds__(TPB) chamfer_old(const float4* __restrict__ q4,
                                                   int* __restrict__ minbuf) {
    int b = blockIdx.x;
    int dir = b & 1;
    int rest = b >> 1;
    int jc = rest & (OSPLIT - 1);
    int qt = rest >> 6;
    const float4* __restrict__ qp = q4 + (dir ? N : 0);
    const float4* __restrict__ rp = q4 + (dir ? 0 : N);
    int ibase = qt * OQTILE + (int)threadIdx.x;
    float m2x[OQPT], m2y[OQPT], m2z[OQPT], qw[OQPT], vmin[OQPT];
#pragma unroll
    for (int q = 0; q < OQPT; ++q) {
        float4 qq = qp[ibase + q * TPB];
        m2x[q] = -2.0f * qq.x; m2y[q] = -2.0f * qq.y; m2z[q] = -2.0f * qq.z;
        qw[q] = qq.w; vmin[q] = __builtin_inff();
    }
    int j0 = jc * OCHUNK;
    float4 ra = rp[j0];
    float4 rb = rp[j0 + 1];
#pragma unroll 2
    for (int j = j0; j < j0 + OCHUNK; j += 2) {
        float4 na = rp[j + 2];
        float4 nb = rp[j + 3];
        float raw = ra.w, rbw = rb.w;
#pragma unroll
        for (int q = 0; q < OQPT; ++q) {
            float ta = __builtin_fmaf(ra.x, m2x[q],
                       __builtin_fmaf(ra.y, m2y[q],
                       __builtin_fmaf(ra.z, m2z[q], raw)));
            float tb = __builtin_fmaf(rb.x, m2x[q],
                       __builtin_fmaf(rb.y, m2y[q],
                       __builtin_fmaf(rb.z, m2z[q], rbw)));
            vmin[q] = fminf(vmin[q], fminf(ta, tb));
        }
        ra = na; rb = nb;
    }
#pragma unroll
    for (int q = 0; q < OQPT; ++q) {
        float m = fmaxf(vmin[q] + qw[q], 0.0f);
        atomicMin(&minbuf[dir * N + ibase + q * TPB], __float_as_int(m));
    }
}

// ================= launcher =================
extern "C" void kernel_launch(void* const* d_in, const int* in_sizes, int n_in,
                              void* d_out, int out_size, void* d_ws, size_t ws_size,
                              hipStream_t stream) {
    const float* p_hat = (const float*)d_in[0];
    const float* p     = (const float*)d_in[1];
    float* out = (float*)d_out;
    if (ws_size >= WS_NEED_MFMA) {
        uint4* frags = (uint4*)d_ws;
        int* minbuf  = (int*)((char*)d_ws + 4ull * FRAG_U4 * sizeof(uint4));
        pack_mfma<<<(2 * N + TPB - 1) / TPB, TPB, 0, stream>>>(p_hat, p, frags, minbuf);
        chamfer_mfma<<<NBLK_MFMA, TPB, 0, stream>>>(frags, minbuf);
        reduce_kernel<<<1, 1024, 0, stream>>>(minbuf, out);
    } else {
        float4* q4  = (float4*)d_ws;
        int* minbuf = (int*)((char*)d_ws + 2 * N * sizeof(float4));
        pack_old<<<(2 * N + TPB - 1) / TPB, TPB, 0, stream>>>(p_hat, p, q4, minbuf);
        chamfer_old<<<OGRID, TPB, 0, stream>>>(q4, minbuf);
        reduce_kernel<<<1, 1024, 0, stream>>>(minbuf, out);
    }
}